// Round 4
// baseline (30513.809 us; speedup 1.0000x reference)
//
#include <hip/hip_runtime.h>

// FHN Neural ODE: 19999 RK4(3/8) steps of a 2-64-64-2 tanh MLP.
// R3 design: 4 waves (block=256) cooperatively evaluate the MLP.
//  - R0-R2 evidence: compiler refuses to keep a 64-float/lane W2 working set
//    in VGPRs (VGPR_Count pinned at 44-48 across 3 source variants; per-eval
//    scratch reloads dominate at ~875 cyc/eval). Fix: need only 16 W2
//    floats/lane by splitting layer-2's K dimension across 4 waves.
//  - Every wave computes layer 1 redundantly (y is uniform, h1 identical in
//    all waves), does a 16-wide K-slice of layer 2 (16 readlane+fma), writes
//    its 64 partials to LDS, one __syncthreads (double-buffered slots), then
//    every wave folds the 4 partials and finishes layer 3 + RK4 redundantly
//    and bit-identically (DPP wave reduction -> uniform).

__device__ __forceinline__ float fast_tanh(float x) {
    // tanh(x) = 1 - 2/(exp(2x)+1); saturates correctly at +-inf.
    float e = __expf(2.0f * x);
    float r = __builtin_amdgcn_rcpf(e + 1.0f);
    return fmaf(-2.0f, r, 1.0f);
}

template <int CTRL>
__device__ __forceinline__ float dpp_add(float x) {
    int t = __builtin_amdgcn_update_dpp(0, __float_as_int(x), CTRL, 0xf, 0xf, false);
    return x + __int_as_float(t);
}

// Full-wave64 sum; total lands in lane 63, returned wave-uniform via readlane.
__device__ __forceinline__ float wave_sum_uniform(float x) {
    x = dpp_add<0x111>(x);  // row_shr:1
    x = dpp_add<0x112>(x);  // row_shr:2
    x = dpp_add<0x114>(x);  // row_shr:4
    x = dpp_add<0x118>(x);  // row_shr:8
    x = dpp_add<0x142>(x);  // row_bcast:15
    x = dpp_add<0x143>(x);  // row_bcast:31
    return __int_as_float(__builtin_amdgcn_readlane(__float_as_int(x), 63));
}

extern "C" __global__ void __launch_bounds__(256, 1)
fhn_ode_kernel(const float* __restrict__ t,
               const float* __restrict__ v0,
               const float* __restrict__ W1, const float* __restrict__ b1,
               const float* __restrict__ W2, const float* __restrict__ b2,
               const float* __restrict__ W3, const float* __restrict__ b3,
               const float* __restrict__ w0,
               float* __restrict__ out, int T)
{
    const int tid   = threadIdx.x;
    const int lane  = tid & 63;
    const int wave  = tid >> 6;
    const int kbase = wave << 4;          // this wave's K-slice start

    __shared__ float parts[2][256];       // [buf][wave*64 + lane]

    // Per-lane parameters (identical across waves; lane i = neuron i).
    const float w1a = W1[2 * lane];
    const float w1b = W1[2 * lane + 1];
    const float b1v = b1[lane];
    const float b2v = (wave == 0) ? b2[lane] : 0.0f;  // bias folded into wave 0's partial
    const float w3a = W3[lane];
    const float w3b = W3[64 + lane];
    const float b3a = b3[0];
    const float b3b = b3[1];

    // This wave's 16-wide K-slice of W2 row `lane`: 4 named float4s (16 VGPRs).
    const float4* wp = reinterpret_cast<const float4*>(W2 + 64 * lane + kbase);
    float4 q0 = wp[0], q1 = wp[1], q2 = wp[2], q3 = wp[3];
    asm volatile("" : "+v"(q0.x), "+v"(q0.y), "+v"(q0.z), "+v"(q0.w));
    asm volatile("" : "+v"(q1.x), "+v"(q1.y), "+v"(q1.z), "+v"(q1.w));
    asm volatile("" : "+v"(q2.x), "+v"(q2.y), "+v"(q2.z), "+v"(q2.w));
    asm volatile("" : "+v"(q3.x), "+v"(q3.y), "+v"(q3.z), "+v"(q3.w));

#define RL(j) __int_as_float(__builtin_amdgcn_readlane(hb, kbase + (j)))

    // One MLP eval. buf alternates 0/1 per eval; with double buffering a
    // single barrier per eval is hazard-free (writes to a slot are always
    // two barriers after the last reads of that slot).
    auto mlp_eval = [&](float y0v, float y1v, int buf, float& o0, float& o1) {
        float h1 = fast_tanh(fmaf(w1a, y0v, fmaf(w1b, y1v, b1v)));
        int hb = __float_as_int(h1);
        // 16-wide K-slice, 4 independent accumulator chains.
        float a0 = b2v, a1 = 0.0f, a2 = 0.0f, a3 = 0.0f;
        a0 = fmaf(q0.x, RL(0),  a0);
        a1 = fmaf(q0.y, RL(1),  a1);
        a2 = fmaf(q0.z, RL(2),  a2);
        a3 = fmaf(q0.w, RL(3),  a3);
        a0 = fmaf(q1.x, RL(4),  a0);
        a1 = fmaf(q1.y, RL(5),  a1);
        a2 = fmaf(q1.z, RL(6),  a2);
        a3 = fmaf(q1.w, RL(7),  a3);
        a0 = fmaf(q2.x, RL(8),  a0);
        a1 = fmaf(q2.y, RL(9),  a1);
        a2 = fmaf(q2.z, RL(10), a2);
        a3 = fmaf(q2.w, RL(11), a3);
        a0 = fmaf(q3.x, RL(12), a0);
        a1 = fmaf(q3.y, RL(13), a1);
        a2 = fmaf(q3.z, RL(14), a2);
        a3 = fmaf(q3.w, RL(15), a3);
        parts[buf][(wave << 6) + lane] = (a0 + a1) + (a2 + a3);
        __syncthreads();
        float p = (parts[buf][lane]       + parts[buf][64 + lane]) +
                  (parts[buf][128 + lane] + parts[buf][192 + lane]);
        float h2 = fast_tanh(p);
        // Layer 3: two DPP wave reductions; identical result in every wave.
        o0 = wave_sum_uniform(w3a * h2) + b3a;
        o1 = wave_sum_uniform(w3b * h2) + b3b;
    };

    float y0 = v0[0];
    float y1 = w0[0];
    if (tid == 0) {
        reinterpret_cast<float2*>(out)[0] = make_float2(y0, y1);
    }

    const float third = 1.0f / 3.0f;
    float tc = t[0];
    float tn = t[1];

    for (int i = 1; i < T; ++i) {
        float dt = tn - tc;
        tc = tn;
        int nx = (i + 1 < T) ? (i + 1) : i;
        tn = t[nx];  // uniform load, consumed next iteration (latency hidden)

        float k1x, k1y, k2x, k2y, k3x, k3y, k4x, k4y;
        mlp_eval(y0, y1, 0, k1x, k1y);
        mlp_eval(y0 + dt * k1x * third,
                 y1 + dt * k1y * third, 1, k2x, k2y);
        mlp_eval(y0 + dt * (k2x - k1x * third),
                 y1 + dt * (k2y - k1y * third), 0, k3x, k3y);
        mlp_eval(y0 + dt * (k1x - k2x + k3x),
                 y1 + dt * (k1y - k2y + k3y), 1, k4x, k4y);

        float s = dt * 0.125f;
        y0 = y0 + (k1x + 3.0f * (k2x + k3x) + k4x) * s;
        y1 = y1 + (k1y + 3.0f * (k2y + k3y) + k4y) * s;

        if (tid == 0) {
            reinterpret_cast<float2*>(out)[i] = make_float2(y0, y1);
        }
    }
#undef RL
}

extern "C" void kernel_launch(void* const* d_in, const int* in_sizes, int n_in,
                              void* d_out, int out_size, void* d_ws, size_t ws_size,
                              hipStream_t stream) {
    const float* t  = (const float*)d_in[0];
    const float* v0 = (const float*)d_in[1];
    const float* W1 = (const float*)d_in[2];
    const float* b1 = (const float*)d_in[3];
    const float* W2 = (const float*)d_in[4];
    const float* b2 = (const float*)d_in[5];
    const float* W3 = (const float*)d_in[6];
    const float* b3 = (const float*)d_in[7];
    const float* w0 = (const float*)d_in[8];
    float* out = (float*)d_out;
    int T = in_sizes[0];

    hipLaunchKernelGGL(fhn_ode_kernel, dim3(1), dim3(256), 0, stream,
                       t, v0, W1, b1, W2, b2, W3, b3, w0, out, T);
}

// Round 5
// 27433.752 us; speedup vs baseline: 1.1123x; 1.1123x over previous
//
#include <hip/hip_runtime.h>

// FHN Neural ODE: 19999 RK4(3/8) steps of a 2-64-64-2 tanh MLP.
// R5 design: SINGLE wave64 (no __syncthreads in the hot loop at all).
//  - R4 post-mortem: 16-weight slice was register-resident (VGPR=28) yet time
//    unchanged -> the cost was never W2 reloads; it's (a) readlane->SGPR->fma
//    hazard stalls (~8cyc x N) and (b) the 4-wave barrier+fold (~400 cyc).
//  - This version eliminates both: h1 is broadcast via SAME-ADDRESS
//    ds_read_b128 (HW broadcast, results are VGPRs -> VGPR x VGPR pk-fma, no
//    SGPR hazards); cross-lane reduction only at layer 3 (2 DPP trees).
//  - Weights: j=0..15 of each row in registers (R4-proven size); j=16..63
//    streamed from LDS in a conflict-free float4 layout (addr = 16*lane:
//    every 8-lane group covers banks 0..31 exactly once -> 8 cyc/read).
//    These reads don't depend on h1, so they pipeline under the tanh.

typedef float v2f __attribute__((ext_vector_type(2)));

__device__ __forceinline__ v2f fma2(v2f a, v2f b, v2f c) {
    return __builtin_elementwise_fma(a, b, c);   // v_pk_fma_f32
}

__device__ __forceinline__ float fast_tanh(float x) {
    // tanh(x) = 1 - 2/(exp(2x)+1); saturates correctly at +-inf.
    float e = __expf(2.0f * x);
    float r = __builtin_amdgcn_rcpf(e + 1.0f);
    return fmaf(-2.0f, r, 1.0f);
}

template <int CTRL>
__device__ __forceinline__ float dpp_add(float x) {
    int t = __builtin_amdgcn_update_dpp(0, __float_as_int(x), CTRL, 0xf, 0xf, false);
    return x + __int_as_float(t);
}

// Full-wave64 sum; total lands in lane 63, returned wave-uniform via readlane.
__device__ __forceinline__ float wave_sum_uniform(float x) {
    x = dpp_add<0x111>(x);  // row_shr:1
    x = dpp_add<0x112>(x);  // row_shr:2
    x = dpp_add<0x114>(x);  // row_shr:4
    x = dpp_add<0x118>(x);  // row_shr:8
    x = dpp_add<0x142>(x);  // row_bcast:15
    x = dpp_add<0x143>(x);  // row_bcast:31
    return __int_as_float(__builtin_amdgcn_readlane(__float_as_int(x), 63));
}

extern "C" __global__ void
__attribute__((amdgpu_flat_work_group_size(64, 64), amdgpu_waves_per_eu(1, 1)))
fhn_ode_kernel(const float* __restrict__ t,
               const float* __restrict__ v0,
               const float* __restrict__ W1, const float* __restrict__ b1,
               const float* __restrict__ W2, const float* __restrict__ b2,
               const float* __restrict__ W3, const float* __restrict__ b3,
               const float* __restrict__ w0,
               float* __restrict__ out, int T)
{
    const int lane = threadIdx.x;

    // W2L[s][lane] = float4(W2[lane][16 + 4s .. 19 + 4s]), s = 0..11
    __shared__ float4 W2L[12 * 64];                 // 12 KiB
    __shared__ __align__(16) float h1buf[2][64];    // double-buffered h1

    const float w1a = W1[2 * lane];
    const float w1b = W1[2 * lane + 1];
    const float b1v = b1[lane];
    const float b2v = b2[lane];
    const float w3a = W3[lane];
    const float w3b = W3[64 + lane];
    const float b3a = b3[0];
    const float b3b = b3[1];

    // j = 0..15 of row `lane` in registers (R4-proven resident size).
    const float4* wrow = reinterpret_cast<const float4*>(W2 + 64 * lane);
    float4 q0 = wrow[0], q1 = wrow[1], q2 = wrow[2], q3 = wrow[3];
    asm volatile("" : "+v"(q0.x), "+v"(q0.y), "+v"(q0.z), "+v"(q0.w));
    asm volatile("" : "+v"(q1.x), "+v"(q1.y), "+v"(q1.z), "+v"(q1.w));
    asm volatile("" : "+v"(q2.x), "+v"(q2.y), "+v"(q2.z), "+v"(q2.w));
    asm volatile("" : "+v"(q3.x), "+v"(q3.y), "+v"(q3.z), "+v"(q3.w));

    // j = 16..63 staged to LDS once.
#pragma unroll
    for (int s = 0; s < 12; ++s) {
        W2L[s * 64 + lane] = wrow[s + 4];
    }
    __syncthreads();   // one-time; single wave, just orders LDS init

    // One MLP eval; everything stays inside the wave.
    auto mlp_eval = [&](float y0v, float y1v, int buf, float& o0, float& o1) {
        float h1 = fast_tanh(fmaf(w1a, y0v, fmaf(w1b, y1v, b1v)));
        h1buf[buf][lane] = h1;
        const float4* hb = reinterpret_cast<const float4*>(h1buf[buf]);

        // 8 packed accumulator chains (depth 8 each), 32 v_pk_fma_f32 total.
        v2f aA = {b2v, 0.0f}, aB = {0.0f, 0.0f}, aC = {0.0f, 0.0f}, aD = {0.0f, 0.0f};
        v2f aE = {0.0f, 0.0f}, aF = {0.0f, 0.0f}, aG = {0.0f, 0.0f}, aH = {0.0f, 0.0f};

        // Register part: j = 0..15 (broadcast via same-address ds_read_b128).
        {
            float4 h = hb[0];
            aA = fma2(v2f{q0.x, q0.y}, v2f{h.x, h.y}, aA);
            aB = fma2(v2f{q0.z, q0.w}, v2f{h.z, h.w}, aB);
            h = hb[1];
            aC = fma2(v2f{q1.x, q1.y}, v2f{h.x, h.y}, aC);
            aD = fma2(v2f{q1.z, q1.w}, v2f{h.z, h.w}, aD);
            h = hb[2];
            aE = fma2(v2f{q2.x, q2.y}, v2f{h.x, h.y}, aE);
            aF = fma2(v2f{q2.z, q2.w}, v2f{h.z, h.w}, aF);
            h = hb[3];
            aG = fma2(v2f{q3.x, q3.y}, v2f{h.x, h.y}, aG);
            aH = fma2(v2f{q3.z, q3.w}, v2f{h.z, h.w}, aH);
        }
        // LDS part: j = 16..63. W2L reads are h1-independent (pipeline early);
        // conflict-free layout -> 8 cyc per ds_read_b128.
#pragma unroll
        for (int s = 0; s < 12; s += 2) {
            float4 w0q = W2L[s * 64 + lane];
            float4 h0q = hb[s + 4];
            float4 w1q = W2L[(s + 1) * 64 + lane];
            float4 h1q = hb[s + 5];
            aA = fma2(v2f{w0q.x, w0q.y}, v2f{h0q.x, h0q.y}, aA);
            aB = fma2(v2f{w0q.z, w0q.w}, v2f{h0q.z, h0q.w}, aB);
            aC = fma2(v2f{w1q.x, w1q.y}, v2f{h1q.x, h1q.y}, aC);
            aD = fma2(v2f{w1q.z, w1q.w}, v2f{h1q.z, h1q.w}, aD);
        }

        v2f sv = ((aA + aB) + (aC + aD)) + ((aE + aF) + (aG + aH));
        float h2 = fast_tanh(sv.x + sv.y);

        // Layer 3: two interleaved DPP wave reductions -> uniform outputs.
        o0 = wave_sum_uniform(w3a * h2) + b3a;
        o1 = wave_sum_uniform(w3b * h2) + b3b;
    };

    float y0 = v0[0];
    float y1 = w0[0];
    if (lane == 0) {
        reinterpret_cast<float2*>(out)[0] = make_float2(y0, y1);
    }

    const float third = 1.0f / 3.0f;
    float tc = t[0];
    float tn = t[1];

    for (int i = 1; i < T; ++i) {
        float dt = tn - tc;
        tc = tn;
        int nx = (i + 1 < T) ? (i + 1) : i;
        tn = t[nx];  // uniform load, consumed next iteration (latency hidden)

        float k1x, k1y, k2x, k2y, k3x, k3y, k4x, k4y;
        mlp_eval(y0, y1, 0, k1x, k1y);
        mlp_eval(y0 + dt * k1x * third,
                 y1 + dt * k1y * third, 1, k2x, k2y);
        mlp_eval(y0 + dt * (k2x - k1x * third),
                 y1 + dt * (k2y - k1y * third), 0, k3x, k3y);
        mlp_eval(y0 + dt * (k1x - k2x + k3x),
                 y1 + dt * (k1y - k2y + k3y), 1, k4x, k4y);

        float s = dt * 0.125f;
        y0 = y0 + (k1x + 3.0f * (k2x + k3x) + k4x) * s;
        y1 = y1 + (k1y + 3.0f * (k2y + k3y) + k4y) * s;

        if (lane == 0) {
            reinterpret_cast<float2*>(out)[i] = make_float2(y0, y1);
        }
    }
}

extern "C" void kernel_launch(void* const* d_in, const int* in_sizes, int n_in,
                              void* d_out, int out_size, void* d_ws, size_t ws_size,
                              hipStream_t stream) {
    const float* t  = (const float*)d_in[0];
    const float* v0 = (const float*)d_in[1];
    const float* W1 = (const float*)d_in[2];
    const float* b1 = (const float*)d_in[3];
    const float* W2 = (const float*)d_in[4];
    const float* b2 = (const float*)d_in[5];
    const float* W3 = (const float*)d_in[6];
    const float* b3 = (const float*)d_in[7];
    const float* w0 = (const float*)d_in[8];
    float* out = (float*)d_out;
    int T = in_sizes[0];

    hipLaunchKernelGGL(fhn_ode_kernel, dim3(1), dim3(64), 0, stream,
                       t, v0, W1, b1, W2, b2, W3, b3, w0, out, T);
}